// Round 1
// baseline (696.636 us; speedup 1.0000x reference)
//
#include <hip/hip_runtime.h>

// Problem constants
#define NB   2
#define NN   4
#define ND   256
#define NP   30000
#define NIMG 8            // NB*NN
#define NSEG 57600        // NB*60*60*8
#define NROWS 60000       // NB*NP

// ws layout (float offsets; all even so the double region stays 8B aligned)
static const size_t OFF_S     = 0;                      // 15,360,000 floats (B,D,P)
static const size_t OFF_C1P   = OFF_S   + 15360000ull;  // conv1 split-K partials: 4*32768
static const size_t OFF_C1    = OFF_C1P + 131072ull;    // conv1 rows 0..1: (8,64,2,32)
static const size_t OFF_C2    = OFF_C1  + 32768ull;     // conv2 row 0: (8,64,64)
static const size_t OFF_C3    = OFF_C2  + 32768ull;     // conv3 row 0: (8,256,128)
static const size_t OFF_FM    = OFF_C3  + 262144ull;    // fm row 0: (8,256,256)
static const size_t OFF_CNT   = OFF_FM  + 524288ull;    // 57600 floats
static const size_t OFF_SCALE = OFF_CNT + 57600ull;     // 256
static const size_t OFF_SHIFT = OFF_SCALE + 256ull;     // 256
static const size_t OFF_SUM   = OFF_SHIFT + 256ull;     // 256 doubles = 512 floats
static const size_t OFF_SUMSQ = OFF_SUM + 512ull;       // 256 doubles

// ---------------- conv1: rows 0..1 only, split-K over ic (4 x 64) ----------------
__global__ void conv1_partial_k(const float* __restrict__ in, const float* __restrict__ w1,
                                float* __restrict__ part) {
    int t = blockIdx.x * blockDim.x + threadIdx.x;   // 131072
    int s = t >> 15;                                 // K split 0..3
    int o = t & 32767;                               // ((img*64+oc)*2+r)*32+c
    int c   = o & 31;
    int r   = (o >> 5) & 1;
    int oc  = (o >> 6) & 63;
    int img = o >> 12;
    float acc = 0.f;
    int krlo = 3 - r;                                // valid kernel rows: out row r uses in rows r-3+kr >= 0
    for (int ic = s * 64; ic < s * 64 + 64; ++ic) {
        const float* inp = in + (size_t)(img * 256 + ic) * 1024;
        const float* wp  = w1 + (size_t)(oc * 256 + ic) * 49;
        for (int kr = krlo; kr <= 6; ++kr) {
            const float* ip = inp + (r - 3 + kr) * 32;
            const float* wr = wp + kr * 7;
#pragma unroll
            for (int kc = 0; kc < 7; ++kc) {
                int cc = c - 3 + kc;
                if (cc >= 0 && cc < 32) acc += ip[cc] * wr[kc];
            }
        }
    }
    part[t] = acc;
}

__global__ void conv1_reduce_k(const float* __restrict__ part, float* __restrict__ conv1) {
    int o = blockIdx.x * blockDim.x + threadIdx.x;   // 32768
    float a = part[o] + part[32768 + o] + part[65536 + o] + part[98304 + o];
    conv1[o] = fmaxf(a, 0.f);
}

// ---------------- conv2: output row 0 only; input = nearest2x of conv1 rows 0..1 ----------------
__global__ void conv2_k(const float* __restrict__ conv1, const float* __restrict__ w2,
                        float* __restrict__ conv2) {
    int o = blockIdx.x * blockDim.x + threadIdx.x;   // 32768 = (img*64+oc)*64+c2
    int c2  = o & 63;
    int oc  = (o >> 6) & 63;
    int img = o >> 12;
    float acc = 0.f;
    for (int ic = 0; ic < 64; ++ic) {
        const float* cp = conv1 + (size_t)(img * 64 + ic) * 64;  // 2 rows x 32
        const float* wp = w2 + (size_t)(oc * 64 + ic) * 49;
#pragma unroll
        for (int ur = 0; ur < 4; ++ur) {             // up rows 0..3 = conv1 rows 0,0,1,1; kernel rows ur+3
            const float* rowp = cp + (ur >> 1) * 32;
            const float* wr = wp + (ur + 3) * 7;
#pragma unroll
            for (int kc = 0; kc < 7; ++kc) {
                int uc = c2 - 3 + kc;
                if (uc >= 0 && uc < 64) acc += rowp[uc >> 1] * wr[kc];
            }
        }
    }
    conv2[o] = fmaxf(acc, 0.f);
}

// ---------------- conv3: output row 0 only; up2 rows 0,1 both = conv2 row 0 (x-duplicated) ----------------
__global__ void conv3_k(const float* __restrict__ conv2, const float* __restrict__ w3,
                        float* __restrict__ conv3) {
    int o = blockIdx.x * blockDim.x + threadIdx.x;   // 262144 = (img*256+oc)*128+c3
    int c3  = o & 127;
    int oc  = (o >> 7) & 255;
    int img = o >> 15;
    float acc = 0.f;
    for (int ic = 0; ic < 64; ++ic) {
        const float* rp = conv2 + (size_t)(img * 64 + ic) * 64;
        const float* wp = w3 + (size_t)(oc * 64 + ic) * 9;
#pragma unroll
        for (int kc = 0; kc < 3; ++kc) {             // kernel rows 1 and 2 both hit the same row
            int uc = c3 - 1 + kc;
            if (uc >= 0 && uc < 128) acc += rp[uc >> 1] * (wp[3 + kc] + wp[6 + kc]);
        }
    }
    conv3[o] = fmaxf(acc, 0.f);
}

// ---------------- bilinear align_corners x-upsample of row 0: 128 -> 256 ----------------
__global__ void bilin_k(const float* __restrict__ conv3, float* __restrict__ fm) {
    int o = blockIdx.x * blockDim.x + threadIdx.x;   // 524288 = (img*256+d)*256+x
    int x = o & 255;
    int rest = o >> 8;
    const float f = (float)(127.0 / 255.0);
    float pos = (float)x * f;
    float i0f = floorf(pos);
    int i0 = (int)i0f;
    int i1 = min(i0 + 1, 127);
    float w = pos - i0f;
    const float* rp = conv3 + (size_t)rest * 128;
    fm[o] = rp[i0] * (1.f - w) + rp[i1] * w;
}

// ---------------- sample + mean over n + fused BN statistics ----------------
// S is stored flat as (b, d, p); the same buffer reinterpreted as (b*P+p', 256)
// row-major IS the reference's scrambled feats (the .view bug is a free reshape).
// BN column of flat k = (48*d + p) & 255, constant per thread at stride 256.
__global__ void sample_k(const float* __restrict__ fm, const float* __restrict__ pix,
                         float* __restrict__ S, double* __restrict__ sum,
                         double* __restrict__ sumsq) {
    __shared__ float rows[4][256];
    int bd = blockIdx.x;            // b*256 + d
    int b = bd >> 8;
    int d = bd & 255;
    int tid = threadIdx.x;
#pragma unroll
    for (int i = 0; i < 4; ++i) {
        int idx = tid + i * 256;
        int n = idx >> 8, x = idx & 255;
        rows[n][x] = fm[((size_t)((b * 4 + n) * 256 + d)) * 256 + x];
    }
    __syncthreads();
    const int CHUNK = 7500;
    int p0 = blockIdx.y * CHUNK;
    int p1 = min(p0 + CHUNK, NP);
    float lsum = 0.f, lsq = 0.f;
    for (int p = p0 + tid; p < p1; p += 256) {
        float acc = 0.f;
#pragma unroll
        for (int n = 0; n < 4; ++n) {
            float px = pix[(((size_t)(b * 4 + n)) * NP + p) * 2];
            float gx = px / 256.0f - 1.0f;
            float gy = gx / 256.0f - 1.0f;          // faithful bug: gy from gx
            float ix = ((gx + 1.0f) * 256.0f - 1.0f) * 0.5f;
            float iy = ((gy + 1.0f) * 256.0f - 1.0f) * 0.5f;
            float x0f = floorf(ix), y0f = floorf(iy);
            int x0 = (int)x0f, y0 = (int)y0f;
            float wx1 = ix - x0f, wy1 = iy - y0f;
            float wrow = 0.f;                       // weight landing on fmap row 0
            if (y0 == 0) wrow += 1.0f - wy1;
            if (y0 + 1 == 0) wrow += wy1;
            float v = 0.f;
            if (x0 >= 0 && x0 < 256) v += rows[n][x0] * (1.0f - wx1);
            int x1 = x0 + 1;
            if (x1 >= 0 && x1 < 256) v += rows[n][x1] * wx1;
            acc += wrow * v;
        }
        acc *= 0.25f;                               // mean over N=4
        S[(size_t)bd * NP + p] = acc;
        lsum += acc;
        lsq += acc * acc;
    }
    int dn = (48 * d + p0 + tid) & 255;             // BN column for this thread
    atomicAdd(&sum[dn], (double)lsum);
    atomicAdd(&sumsq[dn], (double)lsq);
}

__global__ void scaleshift_k(const double* __restrict__ sum, const double* __restrict__ sumsq,
                             const float* __restrict__ gamma, const float* __restrict__ beta,
                             float* __restrict__ scale, float* __restrict__ shift) {
    int d = threadIdx.x;
    double mu = sum[d] / 60000.0;
    double var = sumsq[d] / 60000.0 - mu * mu;
    float rs = 1.0f / sqrtf((float)var + 1e-5f);
    float sc = rs * gamma[d];
    scale[d] = sc;
    shift[d] = beta[d] - (float)mu * sc;
}

// ---------------- normalize + scatter-add into dense voxel grid ----------------
__global__ void scatter_k(const float* __restrict__ S, const int* __restrict__ vox,
                          const float* __restrict__ scale, const float* __restrict__ shift,
                          float* __restrict__ out, float* __restrict__ cnt) {
    int r = blockIdx.x;             // row of scrambled feats = b*P + p
    int d = threadIdx.x;
    int v0 = vox[r * 3], v1 = vox[r * 3 + 1], v2 = vox[r * 3 + 2];
    int b = r / NP;
    int lin = ((b * 60 + v0) * 60 + v1) * 8 + v2;
    float val = fmaf(S[(size_t)r * 256 + d], scale[d], shift[d]);
    atomicAdd(&out[(size_t)lin * 256 + d], val);
    if (d == 0) atomicAdd(&cnt[lin], 1.0f);
}

__global__ void finalize_k(float* __restrict__ out, const float* __restrict__ cnt,
                           float* __restrict__ coors) {
    int v = blockIdx.x;             // 0..57599
    int d = threadIdx.x;
    float dn = fmaxf(cnt[v], 1.0f);
    out[(size_t)v * 256 + d] = out[(size_t)v * 256 + d] / dn;
    if (d < 4) {
        int bb = v / 28800, rr = v % 28800;
        int val = (d == 0) ? bb : (d == 1) ? rr / 480 : (d == 2) ? (rr % 480) / 8 : rr % 8;
        coors[(size_t)v * 4 + d] = (float)val;
    }
}

extern "C" void kernel_launch(void* const* d_in, const int* in_sizes, int n_in,
                              void* d_out, int out_size, void* d_ws, size_t ws_size,
                              hipStream_t stream) {
    const float* clip  = (const float*)d_in[0];
    const float* pix   = (const float*)d_in[1];
    const int*   vox   = (const int*)d_in[2];
    const float* w1    = (const float*)d_in[3];
    const float* w2    = (const float*)d_in[4];
    const float* w3    = (const float*)d_in[5];
    const float* gamma = (const float*)d_in[6];
    const float* beta  = (const float*)d_in[7];
    float* out = (float*)d_out;
    float* ws  = (float*)d_ws;

    float*  S     = ws + OFF_S;
    float*  c1p   = ws + OFF_C1P;
    float*  c1    = ws + OFF_C1;
    float*  c2    = ws + OFF_C2;
    float*  c3    = ws + OFF_C3;
    float*  fm    = ws + OFF_FM;
    float*  cnt   = ws + OFF_CNT;
    float*  scale = ws + OFF_SCALE;
    float*  shift = ws + OFF_SHIFT;
    double* sum   = (double*)(ws + OFF_SUM);
    double* sumsq = (double*)(ws + OFF_SUMSQ);

    // zero the accumulators (harness poisons d_out/d_ws with 0xAA every call)
    hipMemsetAsync(out, 0, (size_t)NSEG * 256 * sizeof(float), stream);
    hipMemsetAsync(cnt, 0, (size_t)NSEG * sizeof(float), stream);
    hipMemsetAsync((void*)sum, 0, 2 * 256 * sizeof(double), stream);

    conv1_partial_k<<<512, 256, 0, stream>>>(clip, w1, c1p);
    conv1_reduce_k<<<128, 256, 0, stream>>>(c1p, c1);
    conv2_k<<<128, 256, 0, stream>>>(c1, w2, c2);
    conv3_k<<<1024, 256, 0, stream>>>(c2, w3, c3);
    bilin_k<<<2048, 256, 0, stream>>>(c3, fm);
    sample_k<<<dim3(512, 4), 256, 0, stream>>>(fm, pix, S, sum, sumsq);
    scaleshift_k<<<1, 256, 0, stream>>>(sum, sumsq, gamma, beta, scale, shift);
    scatter_k<<<NROWS, 256, 0, stream>>>(S, vox, scale, shift, out, cnt);
    finalize_k<<<NSEG, 256, 0, stream>>>(out, cnt, out + (size_t)NSEG * 256);
}

// Round 4
// 449.607 us; speedup vs baseline: 1.5494x; 1.5494x over previous
//
#include <hip/hip_runtime.h>

// Problem constants
#define NB   2
#define NN   4
#define ND   256
#define NP   30000
#define NSEG 57600        // NB*60*60*8
#define NROWS 60000       // NB*NP

// ws layout (float offsets; all even so the double region stays 8B aligned)
// Conv partial-sum scratch is ALIASED into the S region: all conv partials are
// produced and consumed before sample_k writes S.
static const size_t OFF_S     = 0;                      // 15,360,000 floats (B,D,P)
static const size_t OFF_C1P   = OFF_S;                  // 32*32768 = 1,048,576
static const size_t OFF_C2P   = OFF_S + 2000000ull;     // 8*32768  = 262,144
static const size_t OFF_C3P   = OFF_S + 4000000ull;     // 4*262144 = 1,048,576
static const size_t OFF_C1    = OFF_S   + 15360000ull;  // conv1 rows 0..1: (8,64,2,32)
static const size_t OFF_C2    = OFF_C1  + 32768ull;     // conv2 row 0: (8,64,64)
static const size_t OFF_C3    = OFF_C2  + 32768ull;     // conv3 row 0: (8,256,128)
static const size_t OFF_FM    = OFF_C3  + 262144ull;    // fm row 0: (8,256,256)
static const size_t OFF_CNT   = OFF_FM  + 524288ull;    // 57600 floats
static const size_t OFF_SCALE = OFF_CNT + 57600ull;     // 256
static const size_t OFF_SHIFT = OFF_SCALE + 256ull;     // 256
static const size_t OFF_SUM   = OFF_SHIFT + 256ull;     // 256 doubles = 512 floats
static const size_t OFF_SUMSQ = OFF_SUM + 512ull;       // 256 doubles

// ---------------- conv1: rows 0..1 only, split-K over ic (32 x 8) ----------------
__global__ void conv1_partial_k(const float* __restrict__ in, const float* __restrict__ w1,
                                float* __restrict__ part) {
    int t = blockIdx.x * blockDim.x + threadIdx.x;   // 1,048,576
    int s = t >> 15;                                 // K split 0..31 (8 ic each)
    int o = t & 32767;                               // ((img*64+oc)*2+r)*32+c
    int c   = o & 31;
    int r   = (o >> 5) & 1;
    int oc  = (o >> 6) & 63;
    int img = o >> 12;
    float acc = 0.f;
    int krlo = 3 - r;                                // out row r uses in rows r-3+kr >= 0
#pragma unroll
    for (int i = 0; i < 8; ++i) {
        int ic = s * 8 + i;
        const float* inp = in + (size_t)(img * 256 + ic) * 1024;
        const float* wp  = w1 + (size_t)(oc * 256 + ic) * 49;
        for (int kr = krlo; kr <= 6; ++kr) {
            const float* ip = inp + (r - 3 + kr) * 32;
            const float* wr = wp + kr * 7;
#pragma unroll
            for (int kc = 0; kc < 7; ++kc) {
                int cc = c - 3 + kc;
                if (cc >= 0 && cc < 32) acc += ip[cc] * wr[kc];
            }
        }
    }
    part[t] = acc;
}

__global__ void conv1_reduce_k(const float* __restrict__ part, float* __restrict__ conv1) {
    int o = blockIdx.x * blockDim.x + threadIdx.x;   // 32768
    float a = 0.f;
#pragma unroll
    for (int s = 0; s < 32; ++s) a += part[(size_t)s * 32768 + o];
    conv1[o] = fmaxf(a, 0.f);
}

// ---------------- conv2: output row 0 only; split-K over ic (8 x 8) ----------------
__global__ void conv2_partial_k(const float* __restrict__ conv1, const float* __restrict__ w2,
                                float* __restrict__ part) {
    int t = blockIdx.x * blockDim.x + threadIdx.x;   // 262,144
    int s = t >> 15;                                 // 0..7 (8 ic each)
    int o = t & 32767;                               // (img*64+oc)*64+c2
    int c2  = o & 63;
    int oc  = (o >> 6) & 63;
    int img = o >> 12;
    float acc = 0.f;
#pragma unroll
    for (int i = 0; i < 8; ++i) {
        int ic = s * 8 + i;
        const float* cp = conv1 + (size_t)(img * 64 + ic) * 64;  // 2 rows x 32
        const float* wp = w2 + (size_t)(oc * 64 + ic) * 49;
#pragma unroll
        for (int ur = 0; ur < 4; ++ur) {             // up rows 0..3 = conv1 rows 0,0,1,1; kernel rows ur+3
            const float* rowp = cp + (ur >> 1) * 32;
            const float* wr = wp + (ur + 3) * 7;
#pragma unroll
            for (int kc = 0; kc < 7; ++kc) {
                int uc = c2 - 3 + kc;
                if (uc >= 0 && uc < 64) acc += rowp[uc >> 1] * wr[kc];
            }
        }
    }
    part[t] = acc;
}

__global__ void conv2_reduce_k(const float* __restrict__ part, float* __restrict__ conv2) {
    int o = blockIdx.x * blockDim.x + threadIdx.x;   // 32768
    float a = 0.f;
#pragma unroll
    for (int s = 0; s < 8; ++s) a += part[(size_t)s * 32768 + o];
    conv2[o] = fmaxf(a, 0.f);
}

// ---------------- conv3: output row 0 only; split-K over ic (4 x 16) ----------------
__global__ void conv3_partial_k(const float* __restrict__ conv2, const float* __restrict__ w3,
                                float* __restrict__ part) {
    int t = blockIdx.x * blockDim.x + threadIdx.x;   // 1,048,576
    int s = t >> 18;                                 // 0..3 (16 ic each)
    int o = t & 262143;                              // (img*256+oc)*128+c3
    int c3  = o & 127;
    int oc  = (o >> 7) & 255;
    int img = o >> 15;
    float acc = 0.f;
#pragma unroll
    for (int i = 0; i < 16; ++i) {
        int ic = s * 16 + i;
        const float* rp = conv2 + (size_t)(img * 64 + ic) * 64;
        const float* wp = w3 + (size_t)(oc * 64 + ic) * 9;
#pragma unroll
        for (int kc = 0; kc < 3; ++kc) {             // kernel rows 1 and 2 both hit the same row
            int uc = c3 - 1 + kc;
            if (uc >= 0 && uc < 128) acc += rp[uc >> 1] * (wp[3 + kc] + wp[6 + kc]);
        }
    }
    part[t] = acc;
}

__global__ void conv3_reduce_k(const float* __restrict__ part, float* __restrict__ conv3) {
    int o = blockIdx.x * blockDim.x + threadIdx.x;   // 262,144
    float a = part[o] + part[262144 + o] + part[524288 + o] + part[786432 + o];
    conv3[o] = fmaxf(a, 0.f);
}

// ---------------- bilinear align_corners x-upsample of row 0: 128 -> 256 ----------------
__global__ void bilin_k(const float* __restrict__ conv3, float* __restrict__ fm) {
    int o = blockIdx.x * blockDim.x + threadIdx.x;   // 524288 = (img*256+d)*256+x
    int x = o & 255;
    int rest = o >> 8;
    const float f = (float)(127.0 / 255.0);
    float pos = (float)x * f;
    float i0f = floorf(pos);
    int i0 = (int)i0f;
    int i1 = min(i0 + 1, 127);
    float w = pos - i0f;
    const float* rp = conv3 + (size_t)rest * 128;
    fm[o] = rp[i0] * (1.f - w) + rp[i1] * w;
}

// ---------------- sample + mean over n + fused BN statistics ----------------
// S flat (b, d, p) reinterpreted as (b*P+p', 256) row-major IS the reference's
// scrambled feats (the .view bug is a free reshape).
// BN column of flat k = (48*d + p) & 255, constant per thread at stride 256.
__global__ void sample_k(const float* __restrict__ fm, const float* __restrict__ pix,
                         float* __restrict__ S, double* __restrict__ sum,
                         double* __restrict__ sumsq) {
    __shared__ float rows[4][256];
    int bd = blockIdx.x;            // b*256 + d
    int b = bd >> 8;
    int d = bd & 255;
    int tid = threadIdx.x;
#pragma unroll
    for (int i = 0; i < 4; ++i) {
        int idx = tid + i * 256;
        int n = idx >> 8, x = idx & 255;
        rows[n][x] = fm[((size_t)((b * 4 + n) * 256 + d)) * 256 + x];
    }
    __syncthreads();
    const int CHUNK = 7500;
    int p0 = blockIdx.y * CHUNK;
    int p1 = min(p0 + CHUNK, NP);
    float lsum = 0.f, lsq = 0.f;
    for (int p = p0 + tid; p < p1; p += 256) {
        float acc = 0.f;
#pragma unroll
        for (int n = 0; n < 4; ++n) {
            float px = pix[(((size_t)(b * 4 + n)) * NP + p) * 2];
            float gx = px / 256.0f - 1.0f;
            float gy = gx / 256.0f - 1.0f;          // faithful bug: gy from gx
            float ix = ((gx + 1.0f) * 256.0f - 1.0f) * 0.5f;
            float iy = ((gy + 1.0f) * 256.0f - 1.0f) * 0.5f;
            float x0f = floorf(ix), y0f = floorf(iy);
            int x0 = (int)x0f, y0 = (int)y0f;
            float wx1 = ix - x0f, wy1 = iy - y0f;
            float wrow = 0.f;                       // weight landing on fmap row 0
            if (y0 == 0) wrow += 1.0f - wy1;
            if (y0 + 1 == 0) wrow += wy1;
            float v = 0.f;
            if (x0 >= 0 && x0 < 256) v += rows[n][x0] * (1.0f - wx1);
            int x1 = x0 + 1;
            if (x1 >= 0 && x1 < 256) v += rows[n][x1] * wx1;
            acc += wrow * v;
        }
        acc *= 0.25f;                               // mean over N=4
        S[(size_t)bd * NP + p] = acc;
        lsum += acc;
        lsq += acc * acc;
    }
    int dn = (48 * d + p0 + tid) & 255;             // BN column for this thread
    atomicAdd(&sum[dn], (double)lsum);
    atomicAdd(&sumsq[dn], (double)lsq);
}

__global__ void scaleshift_k(const double* __restrict__ sum, const double* __restrict__ sumsq,
                             const float* __restrict__ gamma, const float* __restrict__ beta,
                             float* __restrict__ scale, float* __restrict__ shift) {
    int d = threadIdx.x;
    double mu = sum[d] / 60000.0;
    double var = sumsq[d] / 60000.0 - mu * mu;
    float rs = 1.0f / sqrtf((float)var + 1e-5f);
    float sc = rs * gamma[d];
    scale[d] = sc;
    shift[d] = beta[d] - (float)mu * sc;
}

// ---------------- normalize + scatter-add into dense voxel grid ----------------
__global__ void scatter_k(const float* __restrict__ S, const int* __restrict__ vox,
                          const float* __restrict__ scale, const float* __restrict__ shift,
                          float* __restrict__ out, float* __restrict__ cnt) {
    int r = blockIdx.x;             // row of scrambled feats = b*P + p
    int d = threadIdx.x;
    int v0 = vox[r * 3], v1 = vox[r * 3 + 1], v2 = vox[r * 3 + 2];
    int b = r / NP;
    int lin = ((b * 60 + v0) * 60 + v1) * 8 + v2;
    float val = fmaf(S[(size_t)r * 256 + d], scale[d], shift[d]);
    atomicAdd(&out[(size_t)lin * 256 + d], val);
    if (d == 0) atomicAdd(&cnt[lin], 1.0f);
}

__global__ void finalize_k(float* __restrict__ out, const float* __restrict__ cnt,
                           float* __restrict__ coors) {
    int v = blockIdx.x;             // 0..57599
    int d = threadIdx.x;
    float dn = fmaxf(cnt[v], 1.0f);
    out[(size_t)v * 256 + d] = out[(size_t)v * 256 + d] / dn;
    if (d < 4) {
        int bb = v / 28800, rr = v % 28800;
        int val = (d == 0) ? bb : (d == 1) ? rr / 480 : (d == 2) ? (rr % 480) / 8 : rr % 8;
        coors[(size_t)v * 4 + d] = (float)val;
    }
}

extern "C" void kernel_launch(void* const* d_in, const int* in_sizes, int n_in,
                              void* d_out, int out_size, void* d_ws, size_t ws_size,
                              hipStream_t stream) {
    const float* clip  = (const float*)d_in[0];
    const float* pix   = (const float*)d_in[1];
    const int*   vox   = (const int*)d_in[2];
    const float* w1    = (const float*)d_in[3];
    const float* w2    = (const float*)d_in[4];
    const float* w3    = (const float*)d_in[5];
    const float* gamma = (const float*)d_in[6];
    const float* beta  = (const float*)d_in[7];
    float* out = (float*)d_out;
    float* ws  = (float*)d_ws;

    float*  S     = ws + OFF_S;
    float*  c1p   = ws + OFF_C1P;   // aliases S (consumed before S written)
    float*  c2p   = ws + OFF_C2P;   // aliases S
    float*  c3p   = ws + OFF_C3P;   // aliases S
    float*  c1    = ws + OFF_C1;
    float*  c2    = ws + OFF_C2;
    float*  c3    = ws + OFF_C3;
    float*  fm    = ws + OFF_FM;
    float*  cnt   = ws + OFF_CNT;
    float*  scale = ws + OFF_SCALE;
    float*  shift = ws + OFF_SHIFT;
    double* sum   = (double*)(ws + OFF_SUM);
    double* sumsq = (double*)(ws + OFF_SUMSQ);

    // zero the accumulators (harness poisons d_out/d_ws with 0xAA every call)
    hipMemsetAsync(out, 0, (size_t)NSEG * 256 * sizeof(float), stream);
    hipMemsetAsync(cnt, 0, (size_t)NSEG * sizeof(float), stream);
    hipMemsetAsync((void*)sum, 0, 2 * 256 * sizeof(double), stream);

    conv1_partial_k<<<4096, 256, 0, stream>>>(clip, w1, c1p);
    conv1_reduce_k<<<128, 256, 0, stream>>>(c1p, c1);
    conv2_partial_k<<<1024, 256, 0, stream>>>(c1, w2, c2p);
    conv2_reduce_k<<<128, 256, 0, stream>>>(c2p, c2);
    conv3_partial_k<<<4096, 256, 0, stream>>>(c2, w3, c3p);
    conv3_reduce_k<<<1024, 256, 0, stream>>>(c3p, c3);
    bilin_k<<<2048, 256, 0, stream>>>(c3, fm);
    sample_k<<<dim3(512, 4), 256, 0, stream>>>(fm, pix, S, sum, sumsq);
    scaleshift_k<<<1, 256, 0, stream>>>(sum, sumsq, gamma, beta, scale, shift);
    scatter_k<<<NROWS, 256, 0, stream>>>(S, vox, scale, shift, out, cnt);
    finalize_k<<<NSEG, 256, 0, stream>>>(out, cnt, out + (size_t)NSEG * 256);
}

// Round 5
// 401.068 us; speedup vs baseline: 1.7370x; 1.1210x over previous
//
#include <hip/hip_runtime.h>

// Problem constants
#define NB   2
#define NN   4
#define ND   256
#define NP   30000
#define NSEG 57600        // NB*60*60*8
#define NROWS 60000       // NB*NP
#define DG   8            // d-values per sampling block

// ws layout (float offsets; all even so the double region stays 8B aligned)
static const size_t OFF_C1P   = 0;                      // 32*32768 = 1,048,576
static const size_t OFF_C2P   = 2000000ull;             // 8*32768  = 262,144
static const size_t OFF_C3P   = 4000000ull;             // 4*262144 = 1,048,576
static const size_t OFF_C1    = 15360000ull;            // conv1 rows 0..1: (8,64,2,32)
static const size_t OFF_C2    = OFF_C1  + 32768ull;     // conv2 row 0: (8,64,64)
static const size_t OFF_C3    = OFF_C2  + 32768ull;     // conv3 row 0: (8,256,128)
static const size_t OFF_FM    = OFF_C3  + 262144ull;    // fm row 0: (8,256,256)
static const size_t OFF_CNT   = OFF_FM  + 524288ull;    // 57600 floats
static const size_t OFF_SCALE = OFF_CNT + 57600ull;     // 256
static const size_t OFF_SHIFT = OFF_SCALE + 256ull;     // 256
static const size_t OFF_SUM   = OFF_SHIFT + 256ull;     // 256 doubles = 512 floats
static const size_t OFF_SUMSQ = OFF_SUM + 512ull;       // 256 doubles

// ---------------- conv1: rows 0..1 only, split-K over ic (32 x 8) ----------------
__global__ void conv1_partial_k(const float* __restrict__ in, const float* __restrict__ w1,
                                float* __restrict__ part) {
    int t = blockIdx.x * blockDim.x + threadIdx.x;   // 1,048,576
    int s = t >> 15;                                 // K split 0..31 (8 ic each)
    int o = t & 32767;                               // ((img*64+oc)*2+r)*32+c
    int c   = o & 31;
    int r   = (o >> 5) & 1;
    int oc  = (o >> 6) & 63;
    int img = o >> 12;
    float acc = 0.f;
    int krlo = 3 - r;
#pragma unroll
    for (int i = 0; i < 8; ++i) {
        int ic = s * 8 + i;
        const float* inp = in + (size_t)(img * 256 + ic) * 1024;
        const float* wp  = w1 + (size_t)(oc * 256 + ic) * 49;
        for (int kr = krlo; kr <= 6; ++kr) {
            const float* ip = inp + (r - 3 + kr) * 32;
            const float* wr = wp + kr * 7;
#pragma unroll
            for (int kc = 0; kc < 7; ++kc) {
                int cc = c - 3 + kc;
                if (cc >= 0 && cc < 32) acc += ip[cc] * wr[kc];
            }
        }
    }
    part[t] = acc;
}

__global__ void conv1_reduce_k(const float* __restrict__ part, float* __restrict__ conv1) {
    int o = blockIdx.x * blockDim.x + threadIdx.x;   // 32768
    float a = 0.f;
#pragma unroll
    for (int s = 0; s < 32; ++s) a += part[(size_t)s * 32768 + o];
    conv1[o] = fmaxf(a, 0.f);
}

// ---------------- conv2: output row 0 only; split-K over ic (8 x 8) ----------------
__global__ void conv2_partial_k(const float* __restrict__ conv1, const float* __restrict__ w2,
                                float* __restrict__ part) {
    int t = blockIdx.x * blockDim.x + threadIdx.x;   // 262,144
    int s = t >> 15;
    int o = t & 32767;                               // (img*64+oc)*64+c2
    int c2  = o & 63;
    int oc  = (o >> 6) & 63;
    int img = o >> 12;
    float acc = 0.f;
#pragma unroll
    for (int i = 0; i < 8; ++i) {
        int ic = s * 8 + i;
        const float* cp = conv1 + (size_t)(img * 64 + ic) * 64;
        const float* wp = w2 + (size_t)(oc * 64 + ic) * 49;
#pragma unroll
        for (int ur = 0; ur < 4; ++ur) {
            const float* rowp = cp + (ur >> 1) * 32;
            const float* wr = wp + (ur + 3) * 7;
#pragma unroll
            for (int kc = 0; kc < 7; ++kc) {
                int uc = c2 - 3 + kc;
                if (uc >= 0 && uc < 64) acc += rowp[uc >> 1] * wr[kc];
            }
        }
    }
    part[t] = acc;
}

__global__ void conv2_reduce_k(const float* __restrict__ part, float* __restrict__ conv2) {
    int o = blockIdx.x * blockDim.x + threadIdx.x;   // 32768
    float a = 0.f;
#pragma unroll
    for (int s = 0; s < 8; ++s) a += part[(size_t)s * 32768 + o];
    conv2[o] = fmaxf(a, 0.f);
}

// ---------------- conv3: output row 0 only; split-K over ic (4 x 16) ----------------
__global__ void conv3_partial_k(const float* __restrict__ conv2, const float* __restrict__ w3,
                                float* __restrict__ part) {
    int t = blockIdx.x * blockDim.x + threadIdx.x;   // 1,048,576
    int s = t >> 18;
    int o = t & 262143;                              // (img*256+oc)*128+c3
    int c3  = o & 127;
    int oc  = (o >> 7) & 255;
    int img = o >> 15;
    float acc = 0.f;
#pragma unroll
    for (int i = 0; i < 16; ++i) {
        int ic = s * 16 + i;
        const float* rp = conv2 + (size_t)(img * 64 + ic) * 64;
        const float* wp = w3 + (size_t)(oc * 64 + ic) * 9;
#pragma unroll
        for (int kc = 0; kc < 3; ++kc) {
            int uc = c3 - 1 + kc;
            if (uc >= 0 && uc < 128) acc += rp[uc >> 1] * (wp[3 + kc] + wp[6 + kc]);
        }
    }
    part[t] = acc;
}

__global__ void conv3_reduce_k(const float* __restrict__ part, float* __restrict__ conv3) {
    int o = blockIdx.x * blockDim.x + threadIdx.x;   // 262,144
    float a = part[o] + part[262144 + o] + part[524288 + o] + part[786432 + o];
    conv3[o] = fmaxf(a, 0.f);
}

// ---------------- bilinear align_corners x-upsample of row 0: 128 -> 256 ----------------
__global__ void bilin_k(const float* __restrict__ conv3, float* __restrict__ fm) {
    int o = blockIdx.x * blockDim.x + threadIdx.x;   // 524288 = (img*256+d)*256+x
    int x = o & 255;
    int rest = o >> 8;
    const float f = (float)(127.0 / 255.0);
    float pos = (float)x * f;
    float i0f = floorf(pos);
    int i0 = (int)i0f;
    int i1 = min(i0 + 1, 127);
    float w = pos - i0f;
    const float* rp = conv3 + (size_t)rest * 128;
    fm[o] = rp[i0] * (1.f - w) + rp[i1] * w;
}

// ---------------- fused sample + mean-over-n + BN stats + raw scatter ----------------
// Flat S index k = (b*256+d)*30000+p maps to feats row r=b*30000+((d*30000+p)>>8),
// col c=(d*30000+p)&255 = (48d+p)&255 (the .view scramble). BN is affine per column
// and scatter-mean is linear, so we scatter RAW sampled values into out[] and apply
// scale/shift in finalize (empty voxels stay exactly 0, matching the reference).
// Each block: one b, DG=8 consecutive d (fm rows in 32KB LDS), pixel math computed
// once per (n,p) and reused across the 8 d's.
__global__ void sample_scatter_k(const float* __restrict__ fm, const float* __restrict__ pix,
                                 const int* __restrict__ vox, float* __restrict__ out,
                                 float* __restrict__ cnt, double* __restrict__ sum,
                                 double* __restrict__ sumsq) {
    __shared__ float rows[4][DG][256];
    __shared__ float bsum[256], bsq[256];
    int bx = blockIdx.x;            // b*32 + dg
    int b  = bx >> 5;
    int d0 = (bx & 31) * DG;
    int tid = threadIdx.x;
#pragma unroll
    for (int i = 0; i < 32; ++i) {  // 4*DG*256 / 256
        int idx = tid + i * 256;
        int x  = idx & 255;
        int dd = (idx >> 8) & (DG - 1);
        int n  = idx >> 11;
        rows[n][dd][x] = fm[((size_t)((b * 4 + n) * 256 + d0 + dd)) * 256 + x];
    }
    bsum[tid] = 0.f;
    bsq[tid]  = 0.f;
    __syncthreads();

    const int CHUNK = 1875;         // 16 chunks * 1875 = 30000
    int p0 = blockIdx.y * CHUNK;
    float lsum[DG], lsq[DG];
#pragma unroll
    for (int dd = 0; dd < DG; ++dd) { lsum[dd] = 0.f; lsq[dd] = 0.f; }

    for (int p = p0 + tid; p < p0 + CHUNK; p += 256) {
        float accv[DG];
#pragma unroll
        for (int dd = 0; dd < DG; ++dd) accv[dd] = 0.f;
#pragma unroll
        for (int n = 0; n < 4; ++n) {
            float px = pix[(((size_t)(b * 4 + n)) * NP + p) * 2];
            float gx = px / 256.0f - 1.0f;
            float gy = gx / 256.0f - 1.0f;          // faithful bug: gy from gx
            float ix = ((gx + 1.0f) * 256.0f - 1.0f) * 0.5f;
            float iy = ((gy + 1.0f) * 256.0f - 1.0f) * 0.5f;
            float x0f = floorf(ix), y0f = floorf(iy);
            int x0 = (int)x0f, y0 = (int)y0f;
            float wx1 = ix - x0f, wy1 = iy - y0f;
            float wrow = 0.f;                       // weight landing on fmap row 0
            if (y0 == 0) wrow += 1.0f - wy1;
            if (y0 + 1 == 0) wrow += wy1;
            bool ok0 = (x0 >= 0) && (x0 < 256);
            int x1 = x0 + 1;
            bool ok1 = (x1 >= 0) && (x1 < 256);
            float w0 = 1.0f - wx1;
            int x0c = ok0 ? x0 : 0;
            int x1c = ok1 ? x1 : 0;
#pragma unroll
            for (int dd = 0; dd < DG; ++dd) {
                float v = 0.f;
                if (ok0) v += rows[n][dd][x0c] * w0;
                if (ok1) v += rows[n][dd][x1c] * wx1;
                accv[dd] += wrow * v;
            }
        }
#pragma unroll
        for (int dd = 0; dd < DG; ++dd) {
            float a = accv[dd] * 0.25f;             // mean over N=4
            int kl = (d0 + dd) * NP + p;            // flat within-batch S index
            int pp = kl >> 8;                       // feats row within batch
            int c  = kl & 255;                      // feats col (BN column)
            int r  = b * NP + pp;
            int v0 = vox[3 * r], v1 = vox[3 * r + 1], v2 = vox[3 * r + 2];
            int lin = ((b * 60 + v0) * 60 + v1) * 8 + v2;
            atomicAdd(&out[(size_t)lin * 256 + c], a);
            if (c == 0) atomicAdd(&cnt[lin], 1.0f);
            lsum[dd] += a;
            lsq[dd]  += a * a;
        }
    }
    // block-level BN-stat reduction: for fixed dd, c = (48*(d0+dd)+p0+tid)&255 is a
    // bijection in tid -> LDS atomics have near-zero contention.
#pragma unroll
    for (int dd = 0; dd < DG; ++dd) {
        int c = (48 * (d0 + dd) + p0 + tid) & 255;
        atomicAdd(&bsum[c], lsum[dd]);
        atomicAdd(&bsq[c], lsq[dd]);
    }
    __syncthreads();
    atomicAdd(&sum[tid], (double)bsum[tid]);
    atomicAdd(&sumsq[tid], (double)bsq[tid]);
}

__global__ void scaleshift_k(const double* __restrict__ sum, const double* __restrict__ sumsq,
                             const float* __restrict__ gamma, const float* __restrict__ beta,
                             float* __restrict__ scale, float* __restrict__ shift) {
    int d = threadIdx.x;
    double mu = sum[d] / 60000.0;
    double var = sumsq[d] / 60000.0 - mu * mu;
    float rs = 1.0f / sqrtf((float)var + 1e-5f);
    float sc = rs * gamma[d];
    scale[d] = sc;
    shift[d] = beta[d] - (float)mu * sc;
}

// ---------------- finalize: mean + affine BN (empty voxels stay 0) + coors ----------------
__global__ void finalize_k(float* __restrict__ out, const float* __restrict__ cnt,
                           const float* __restrict__ scale, const float* __restrict__ shift,
                           float* __restrict__ coors) {
    int v = blockIdx.x;             // 0..57599
    int d = threadIdx.x;
    float n = cnt[v];
    float raw = out[(size_t)v * 256 + d];
    float val = (n > 0.f) ? fmaf(raw / n, scale[d], shift[d]) : 0.f;
    out[(size_t)v * 256 + d] = val;
    if (d < 4) {
        int bb = v / 28800, rr = v % 28800;
        int x = (d == 0) ? bb : (d == 1) ? rr / 480 : (d == 2) ? (rr % 480) / 8 : rr % 8;
        coors[(size_t)v * 4 + d] = (float)x;
    }
}

extern "C" void kernel_launch(void* const* d_in, const int* in_sizes, int n_in,
                              void* d_out, int out_size, void* d_ws, size_t ws_size,
                              hipStream_t stream) {
    const float* clip  = (const float*)d_in[0];
    const float* pix   = (const float*)d_in[1];
    const int*   vox   = (const int*)d_in[2];
    const float* w1    = (const float*)d_in[3];
    const float* w2    = (const float*)d_in[4];
    const float* w3    = (const float*)d_in[5];
    const float* gamma = (const float*)d_in[6];
    const float* beta  = (const float*)d_in[7];
    float* out = (float*)d_out;
    float* ws  = (float*)d_ws;

    float*  c1p   = ws + OFF_C1P;
    float*  c2p   = ws + OFF_C2P;
    float*  c3p   = ws + OFF_C3P;
    float*  c1    = ws + OFF_C1;
    float*  c2    = ws + OFF_C2;
    float*  c3    = ws + OFF_C3;
    float*  fm    = ws + OFF_FM;
    float*  cnt   = ws + OFF_CNT;
    float*  scale = ws + OFF_SCALE;
    float*  shift = ws + OFF_SHIFT;
    double* sum   = (double*)(ws + OFF_SUM);
    double* sumsq = (double*)(ws + OFF_SUMSQ);

    // zero the accumulators (harness poisons d_out/d_ws with 0xAA every call)
    hipMemsetAsync(out, 0, (size_t)NSEG * 256 * sizeof(float), stream);
    hipMemsetAsync(cnt, 0, (size_t)NSEG * sizeof(float), stream);
    hipMemsetAsync((void*)sum, 0, 2 * 256 * sizeof(double), stream);

    conv1_partial_k<<<4096, 256, 0, stream>>>(clip, w1, c1p);
    conv1_reduce_k<<<128, 256, 0, stream>>>(c1p, c1);
    conv2_partial_k<<<1024, 256, 0, stream>>>(c1, w2, c2p);
    conv2_reduce_k<<<128, 256, 0, stream>>>(c2p, c2);
    conv3_partial_k<<<4096, 256, 0, stream>>>(c2, w3, c3p);
    conv3_reduce_k<<<1024, 256, 0, stream>>>(c3p, c3);
    bilin_k<<<2048, 256, 0, stream>>>(c3, fm);
    sample_scatter_k<<<dim3(64, 16), 256, 0, stream>>>(fm, pix, vox, out, cnt, sum, sumsq);
    scaleshift_k<<<1, 256, 0, stream>>>(sum, sumsq, gamma, beta, scale, shift);
    finalize_k<<<NSEG, 256, 0, stream>>>(out, cnt, scale, shift, out + (size_t)NSEG * 256);
}

// Round 6
// 309.816 us; speedup vs baseline: 2.2485x; 1.2945x over previous
//
#include <hip/hip_runtime.h>

// Problem constants
#define NB   2
#define NN   4
#define ND   256
#define NP   30000
#define NSEG 57600        // NB*60*60*8
#define DG   8            // d-values per sampling block

// ws layout (float offsets; all even so the double region stays 8B aligned)
static const size_t OFF_C1P   = 0;                      // 32*32768 = 1,048,576
static const size_t OFF_C2P   = 2000000ull;             // 8*32768  = 262,144
static const size_t OFF_C3P   = 4000000ull;             // 4*262144 = 1,048,576
static const size_t OFF_C1    = 15360000ull;            // conv1 rows 0..1: (8,64,2,32)
static const size_t OFF_C2    = OFF_C1  + 32768ull;     // conv2 row 0: (8,64,64)
static const size_t OFF_C3    = OFF_C2  + 32768ull;     // conv3 row 0: (8,256,128)
static const size_t OFF_FM    = OFF_C3  + 262144ull;    // fm row 0: (8,256,256)
static const size_t OFF_CNT   = OFF_FM  + 524288ull;    // 57600 floats
static const size_t OFF_SCALE = OFF_CNT + 57600ull;     // 256
static const size_t OFF_SHIFT = OFF_SCALE + 256ull;     // 256
static const size_t OFF_SUM   = OFF_SHIFT + 256ull;     // 256 doubles = 512 floats
static const size_t OFF_SUMSQ = OFF_SUM + 512ull;       // 256 doubles

// ---------------- conv1: rows 0..1, split-K 32 x 8ic, LDS-staged, 2 oc/thread ----
// Block: (s, img, ocg of 8 oc). 256 threads = 4 ol x 2 r x 32 c; thread computes
// oc0+ol and oc0+ol+4. Input rows -3..4 zero-padded in LDS -> branch-free 7x7.
__global__ void conv1_partial_k(const float* __restrict__ in, const float* __restrict__ w1,
                                float* __restrict__ part) {
    __shared__ float in_s[8][8][40];   // [ic][row -3..4][3+col, 32 data, pad] 10.2 KB
    __shared__ float w_s[8][8][49];    // [ocl][ic][k] 12.5 KB
    int bx = blockIdx.x;               // 2048 blocks
    int s   = bx >> 6;
    int r6  = bx & 63;
    int img = r6 >> 3;
    int oc0 = (r6 & 7) * 8;
    int tid = threadIdx.x;

    // stage input (guarded read: pads -> 0), 2560 elements
    for (int idx = tid; idx < 2560; idx += 256) {
        int col = idx % 40;
        int row = (idx / 40) & 7;
        int ic  = idx / 320;
        float v = 0.f;
        if (row >= 3 && col >= 3 && col < 35)
            v = in[((size_t)(img * 256 + s * 8 + ic) * 32 + (row - 3)) * 32 + (col - 3)];
        in_s[ic][row][col] = v;
    }
    // stage weights, 3136 elements (contiguous 392-float chunks per ocl)
    for (int idx = tid; idx < 3136; idx += 256) {
        int ocl = idx / 392;
        int rem = idx % 392;
        int ic  = rem / 49;
        int k   = rem % 49;
        w_s[ocl][ic][k] = w1[((size_t)(oc0 + ocl) * 256 + s * 8 + ic) * 49 + k];
    }
    __syncthreads();

    int c  = tid & 31;
    int r  = (tid >> 5) & 1;
    int ol = tid >> 6;
    float a0 = 0.f, a1 = 0.f;
    for (int ic = 0; ic < 8; ++ic) {
        const float* wA = &w_s[ol][ic][0];
        const float* wB = &w_s[ol + 4][ic][0];
#pragma unroll
        for (int kr = 0; kr < 7; ++kr) {
            const float* ip = &in_s[ic][r + kr][c];   // LDS row r+kr = input row r-3+kr
#pragma unroll
            for (int kc = 0; kc < 7; ++kc) {
                float iv = ip[kc];
                a0 += iv * wA[kr * 7 + kc];
                a1 += iv * wB[kr * 7 + kc];
            }
        }
    }
    size_t base = (size_t)s * 32768 + img * 4096 + (oc0 + ol) * 64 + r * 32 + c;
    part[base]       = a0;
    part[base + 256] = a1;   // +4 oc -> +4*64
}

__global__ void conv1_reduce_k(const float* __restrict__ part, float* __restrict__ conv1) {
    int o = blockIdx.x * blockDim.x + threadIdx.x;   // 32768
    float a = 0.f;
#pragma unroll
    for (int s = 0; s < 32; ++s) a += part[(size_t)s * 32768 + o];
    conv1[o] = fmaxf(a, 0.f);
}

// ---------------- conv2: row 0, split-K 8 x 8ic, LDS-staged upsampled rows -------
// Block: (s, img, ocg of 4). 256 threads = 4 ol x 64 c2.
__global__ void conv2_partial_k(const float* __restrict__ conv1, const float* __restrict__ w2,
                                float* __restrict__ part) {
    __shared__ float up_s[8][4][72];   // [ic][ur][3+uc, 64 data, pad] 9.2 KB
    __shared__ float w_s2[4][8][49];   // 6.3 KB
    int bx = blockIdx.x;               // 1024 blocks
    int s   = bx >> 7;
    int r7  = bx & 127;
    int img = r7 >> 4;
    int oc0 = (r7 & 15) * 4;
    int tid = threadIdx.x;

    for (int idx = tid; idx < 2304; idx += 256) {    // 8*4*72
        int col = idx % 72;
        int ur  = (idx / 72) & 3;
        int ic  = idx / 288;
        float v = 0.f;
        if (col >= 3 && col < 67)                    // uc = col-3 in [0,64)
            v = conv1[(size_t)(img * 64 + s * 8 + ic) * 64 + (ur >> 1) * 32 + ((col - 3) >> 1)];
        up_s[ic][ur][col] = v;
    }
    for (int idx = tid; idx < 1568; idx += 256) {    // 4*8*49
        int ocl = idx / 392;
        int rem = idx % 392;
        int ic  = rem / 49;
        int k   = rem % 49;
        w_s2[ocl][ic][k] = w2[((size_t)(oc0 + ocl) * 64 + s * 8 + ic) * 49 + k];
    }
    __syncthreads();

    int c2 = tid & 63;
    int ol = tid >> 6;
    float acc = 0.f;
    for (int ic = 0; ic < 8; ++ic) {
#pragma unroll
        for (int ur = 0; ur < 4; ++ur) {
            const float* ip = &up_s[ic][ur][c2];     // index c2+kc = 3+(c2-3+kc)
            const float* wr = &w_s2[ol][ic][(ur + 3) * 7];
#pragma unroll
            for (int kc = 0; kc < 7; ++kc) acc += ip[kc] * wr[kc];
        }
    }
    part[(size_t)s * 32768 + img * 4096 + (oc0 + ol) * 64 + c2] = acc;
}

__global__ void conv2_reduce_k(const float* __restrict__ part, float* __restrict__ conv2) {
    int o = blockIdx.x * blockDim.x + threadIdx.x;   // 32768
    float a = 0.f;
#pragma unroll
    for (int s = 0; s < 8; ++s) a += part[(size_t)s * 32768 + o];
    conv2[o] = fmaxf(a, 0.f);
}

// ---------------- conv3: row 0, split-K 4 x 16ic, LDS-staged ---------------------
// Block: (s, img, ocg of 2). 256 threads = 2 ol x 128 c3. Kernel rows 1,2 both hit
// conv2 row 0 -> weights combined at stage time.
__global__ void conv3_partial_k(const float* __restrict__ conv2, const float* __restrict__ w3,
                                float* __restrict__ part) {
    __shared__ float row_s[16][132];   // [ic][1+uc, 128 data, pad] 8.4 KB
    __shared__ float wc_s[2][16][4];   // combined w[3+kc]+w[6+kc], 512 B
    int bx = blockIdx.x;               // 4096 blocks
    int s    = bx >> 10;
    int r10  = bx & 1023;
    int img  = r10 >> 7;
    int oc0  = (r10 & 127) * 2;
    int tid  = threadIdx.x;

    for (int idx = tid; idx < 2112; idx += 256) {    // 16*132
        int col = idx % 132;
        int ic  = idx / 132;
        float v = 0.f;
        if (col >= 1 && col < 129)                   // uc = col-1 in [0,128)
            v = conv2[(size_t)(img * 64 + s * 16 + ic) * 64 + ((col - 1) >> 1)];
        row_s[ic][col] = v;
    }
    if (tid < 96) {                                  // 2*16*3
        int ocl = tid / 48;
        int ic  = (tid / 3) % 16;
        int kc  = tid % 3;
        const float* wp = w3 + ((size_t)(oc0 + ocl) * 64 + s * 16 + ic) * 9;
        wc_s[ocl][ic][kc] = wp[3 + kc] + wp[6 + kc];
    }
    __syncthreads();

    int c3 = tid & 127;
    int ol = tid >> 7;
    float acc = 0.f;
    for (int ic = 0; ic < 16; ++ic) {
        const float* ip = &row_s[ic][c3];            // index c3+kc = 1+(c3-1+kc)
#pragma unroll
        for (int kc = 0; kc < 3; ++kc) acc += ip[kc] * wc_s[ol][ic][kc];
    }
    part[(size_t)s * 262144 + img * 32768 + (oc0 + ol) * 128 + c3] = acc;
}

__global__ void conv3_reduce_k(const float* __restrict__ part, float* __restrict__ conv3) {
    int o = blockIdx.x * blockDim.x + threadIdx.x;   // 262,144
    float a = part[o] + part[262144 + o] + part[524288 + o] + part[786432 + o];
    conv3[o] = fmaxf(a, 0.f);
}

// ---------------- bilinear align_corners x-upsample of row 0: 128 -> 256 ---------
__global__ void bilin_k(const float* __restrict__ conv3, float* __restrict__ fm) {
    int o = blockIdx.x * blockDim.x + threadIdx.x;   // 524288 = (img*256+d)*256+x
    int x = o & 255;
    int rest = o >> 8;
    const float f = (float)(127.0 / 255.0);
    float pos = (float)x * f;
    float i0f = floorf(pos);
    int i0 = (int)i0f;
    int i1 = min(i0 + 1, 127);
    float w = pos - i0f;
    const float* rp = conv3 + (size_t)rest * 128;
    fm[o] = rp[i0] * (1.f - w) + rp[i1] * w;
}

// ---------------- fused sample + mean-over-n + BN stats + raw scatter ------------
// LDS tile transposed to [n][x][dd] in bf16: all 8 dd's of one corner = one 16B
// ds_read_b128 (vs 8 scattered b32). BN affine + linear scatter-mean commute, so
// raw samples are scattered; scale/shift applied in finalize (empty voxels stay 0).
// The .view scramble maps a block's 256 consecutive p to 1-2 voxel rows at
// consecutive c -> atomics are coalesced.
__global__ void sample_scatter_k(const float* __restrict__ fm, const float* __restrict__ pix,
                                 const int* __restrict__ vox, float* __restrict__ out,
                                 float* __restrict__ cnt, double* __restrict__ sum,
                                 double* __restrict__ sumsq) {
    __shared__ __align__(16) unsigned short rows_bf[4][256][DG];  // 16 KB
    __shared__ float bsum[256], bsq[256];
    int bx = blockIdx.x;            // b*32 + dgroup
    int b  = bx >> 5;
    int d0 = (bx & 31) * DG;
    int tid = threadIdx.x;

    // stage fm rows -> bf16 (RNE), transposed: x = tid, (n,dd) from i
#pragma unroll
    for (int i = 0; i < 32; ++i) {
        int dd = i & 7;
        int n  = i >> 3;
        float fv = fm[((size_t)((b * 4 + n) * 256 + d0 + dd)) * 256 + tid];
        unsigned u = __float_as_uint(fv);
        u = u + 0x7FFFu + ((u >> 16) & 1u);
        rows_bf[n][tid][dd] = (unsigned short)(u >> 16);
    }
    bsum[tid] = 0.f;
    bsq[tid]  = 0.f;
    __syncthreads();

    const int CHUNK = 1000;         // 30 y-chunks * 1000 = 30000
    int p0 = blockIdx.y * CHUNK;
    float lsum[DG], lsq[DG];
#pragma unroll
    for (int dd = 0; dd < DG; ++dd) { lsum[dd] = 0.f; lsq[dd] = 0.f; }

    for (int p = p0 + tid; p < p0 + CHUNK; p += 256) {
        float acc[DG];
#pragma unroll
        for (int dd = 0; dd < DG; ++dd) acc[dd] = 0.f;
#pragma unroll
        for (int n = 0; n < 4; ++n) {
            float px = pix[(((size_t)(b * 4 + n)) * NP + p) * 2];
            float gx = px / 256.0f - 1.0f;
            float gy = gx / 256.0f - 1.0f;          // faithful bug: gy from gx
            float ix = ((gx + 1.0f) * 256.0f - 1.0f) * 0.5f;
            float iy = ((gy + 1.0f) * 256.0f - 1.0f) * 0.5f;
            float x0f = floorf(ix), y0f = floorf(iy);
            int x0 = (int)x0f, y0 = (int)y0f;
            float wx1 = ix - x0f, wy1 = iy - y0f;
            float wrow = 0.f;                       // weight landing on fmap row 0
            if (y0 == 0) wrow += 1.0f - wy1;
            if (y0 + 1 == 0) wrow += wy1;
            wrow *= 0.25f;                          // fold mean over N=4
            bool ok0 = (x0 >= 0) && (x0 < 256);
            int x1 = x0 + 1;
            bool ok1 = (x1 >= 0) && (x1 < 256);
            float ws0 = ok0 ? wrow * (1.0f - wx1) : 0.f;
            float ws1 = ok1 ? wrow * wx1 : 0.f;
            int x0c = min(max(x0, 0), 255);
            int x1c = min(max(x1, 0), 255);
            uint4 q0 = *(const uint4*)&rows_bf[n][x0c][0];
            uint4 q1 = *(const uint4*)&rows_bf[n][x1c][0];
#define ACC2(j, w0r, w1r)                                                        \
            acc[2*(j)]   += ws0 * __uint_as_float((w0r) << 16)                    \
                          + ws1 * __uint_as_float((w1r) << 16);                   \
            acc[2*(j)+1] += ws0 * __uint_as_float((w0r) & 0xFFFF0000u)            \
                          + ws1 * __uint_as_float((w1r) & 0xFFFF0000u);
            ACC2(0, q0.x, q1.x)
            ACC2(1, q0.y, q1.y)
            ACC2(2, q0.z, q1.z)
            ACC2(3, q0.w, q1.w)
#undef ACC2
        }
#pragma unroll
        for (int dd = 0; dd < DG; ++dd) {
            float a = acc[dd];
            int kl = (d0 + dd) * NP + p;            // flat within-batch S index
            int pp = kl >> 8;                       // feats row within batch
            int cc = kl & 255;                      // feats col (BN column)
            int r  = b * NP + pp;
            int v0 = vox[3 * r], v1 = vox[3 * r + 1], v2 = vox[3 * r + 2];
            int lin = ((b * 60 + v0) * 60 + v1) * 8 + v2;
            atomicAdd(&out[(size_t)lin * 256 + cc], a);
            if (cc == 0) atomicAdd(&cnt[lin], 1.0f);
            lsum[dd] += a;
            lsq[dd]  += a * a;
        }
    }
    // block-level BN-stat reduction: for fixed dd, cc(tid) is a bijection -> no contention
#pragma unroll
    for (int dd = 0; dd < DG; ++dd) {
        int cc = (48 * (d0 + dd) + p0 + tid) & 255;
        atomicAdd(&bsum[cc], lsum[dd]);
        atomicAdd(&bsq[cc], lsq[dd]);
    }
    __syncthreads();
    atomicAdd(&sum[tid], (double)bsum[tid]);
    atomicAdd(&sumsq[tid], (double)bsq[tid]);
}

__global__ void scaleshift_k(const double* __restrict__ sum, const double* __restrict__ sumsq,
                             const float* __restrict__ gamma, const float* __restrict__ beta,
                             float* __restrict__ scale, float* __restrict__ shift) {
    int d = threadIdx.x;
    double mu = sum[d] / 60000.0;
    double var = sumsq[d] / 60000.0 - mu * mu;
    float rs = 1.0f / sqrtf((float)var + 1e-5f);
    float sc = rs * gamma[d];
    scale[d] = sc;
    shift[d] = beta[d] - (float)mu * sc;
}

// ---------------- finalize: mean + affine BN (empty voxels stay 0) + coors -------
__global__ void finalize_k(float* __restrict__ out, const float* __restrict__ cnt,
                           const float* __restrict__ scale, const float* __restrict__ shift,
                           float* __restrict__ coors) {
    int v = blockIdx.x;             // 0..57599
    int d = threadIdx.x;
    float n = cnt[v];
    float raw = out[(size_t)v * 256 + d];
    float val = (n > 0.f) ? fmaf(raw / n, scale[d], shift[d]) : 0.f;
    out[(size_t)v * 256 + d] = val;
    if (d < 4) {
        int bb = v / 28800, rr = v % 28800;
        int x = (d == 0) ? bb : (d == 1) ? rr / 480 : (d == 2) ? (rr % 480) / 8 : rr % 8;
        coors[(size_t)v * 4 + d] = (float)x;
    }
}

extern "C" void kernel_launch(void* const* d_in, const int* in_sizes, int n_in,
                              void* d_out, int out_size, void* d_ws, size_t ws_size,
                              hipStream_t stream) {
    const float* clip  = (const float*)d_in[0];
    const float* pix   = (const float*)d_in[1];
    const int*   vox   = (const int*)d_in[2];
    const float* w1    = (const float*)d_in[3];
    const float* w2    = (const float*)d_in[4];
    const float* w3    = (const float*)d_in[5];
    const float* gamma = (const float*)d_in[6];
    const float* beta  = (const float*)d_in[7];
    float* out = (float*)d_out;
    float* ws  = (float*)d_ws;

    float*  c1p   = ws + OFF_C1P;
    float*  c2p   = ws + OFF_C2P;
    float*  c3p   = ws + OFF_C3P;
    float*  c1    = ws + OFF_C1;
    float*  c2    = ws + OFF_C2;
    float*  c3    = ws + OFF_C3;
    float*  fm    = ws + OFF_FM;
    float*  cnt   = ws + OFF_CNT;
    float*  scale = ws + OFF_SCALE;
    float*  shift = ws + OFF_SHIFT;
    double* sum   = (double*)(ws + OFF_SUM);
    double* sumsq = (double*)(ws + OFF_SUMSQ);

    // zero the accumulators (harness poisons d_out/d_ws with 0xAA every call)
    hipMemsetAsync(out, 0, (size_t)NSEG * 256 * sizeof(float), stream);
    hipMemsetAsync(cnt, 0, (size_t)NSEG * sizeof(float), stream);
    hipMemsetAsync((void*)sum, 0, 2 * 256 * sizeof(double), stream);

    conv1_partial_k<<<2048, 256, 0, stream>>>(clip, w1, c1p);
    conv1_reduce_k<<<128, 256, 0, stream>>>(c1p, c1);
    conv2_partial_k<<<1024, 256, 0, stream>>>(c1, w2, c2p);
    conv2_reduce_k<<<128, 256, 0, stream>>>(c2p, c2);
    conv3_partial_k<<<4096, 256, 0, stream>>>(c2, w3, c3p);
    conv3_reduce_k<<<1024, 256, 0, stream>>>(c3p, c3);
    bilin_k<<<2048, 256, 0, stream>>>(c3, fm);
    sample_scatter_k<<<dim3(64, 30), 256, 0, stream>>>(fm, pix, vox, out, cnt, sum, sumsq);
    scaleshift_k<<<1, 256, 0, stream>>>(sum, sumsq, gamma, beta, scale, shift);
    finalize_k<<<NSEG, 256, 0, stream>>>(out, cnt, scale, shift, out + (size_t)NSEG * 256);
}

// Round 7
// 272.041 us; speedup vs baseline: 2.5608x; 1.1389x over previous
//
#include <hip/hip_runtime.h>

// Problem constants
#define NB   2
#define NN   4
#define ND   256
#define NP   30000
#define NSEG 57600        // NB*60*60*8
#define NROWS 60000       // NB*NP
#define DG   8            // d-values per sampling block
#define CAP  16           // max points per voxel list (Poisson(1.04) max ~9)

// ws layout (float units). Sbf (bf16 S) occupies [0, 7.68M); conv partial
// scratch ALIASES the front of it (consumed by the reduce kernels before
// sample_k writes Sbf).
static const size_t OFF_SBF   = 0;                      // u16[15,360,000] = 7.68M floats
static const size_t OFF_C1P   = 0;                      // 32*32768 = 1,048,576 (alias)
static const size_t OFF_C2P   = 2000000ull;             // 8*32768  = 262,144 (alias)
static const size_t OFF_C3P   = 4000000ull;             // 4*262144 = 1,048,576 (alias)
static const size_t OFF_C1    = 7680000ull;             // conv1 rows 0..1: (8,64,2,32)
static const size_t OFF_C2    = OFF_C1  + 32768ull;     // conv2 row 0: (8,64,64)
static const size_t OFF_C3    = OFF_C2  + 32768ull;     // conv3 row 0: (8,256,128)
static const size_t OFF_FM    = OFF_C3  + 262144ull;    // fm row 0: (8,256,256)
static const size_t OFF_PTAB  = OFF_FM  + 524288ull;    // float4[240,000] = 960,000
static const size_t OFF_CNTI  = OFF_PTAB + 960000ull;   // u32[57,600]
static const size_t OFF_IDX2  = OFF_CNTI + 57600ull;    // u32[57,600*CAP] = 921,600
static const size_t OFF_SCALE = OFF_IDX2 + 921600ull;   // 256
static const size_t OFF_SHIFT = OFF_SCALE + 256ull;     // 256
static const size_t OFF_SUM   = OFF_SHIFT + 256ull;     // 256 doubles = 512 floats
static const size_t OFF_SUMSQ = OFF_SUM + 512ull;       // 256 doubles
// end ~10.47M floats = 41.9 MB (round-1 used 65 MB OK)

__device__ __forceinline__ unsigned short f2bf(float f) {
    unsigned u = __float_as_uint(f);
    u = u + 0x7FFFu + ((u >> 16) & 1u);         // RNE
    return (unsigned short)(u >> 16);
}
__device__ __forceinline__ float bf2f(unsigned short h) {
    return __uint_as_float(((unsigned)h) << 16);
}

// ---------------- conv1: rows 0..1, split-K 32 x 8ic, LDS-staged, 2 oc/thread ----
__global__ void conv1_partial_k(const float* __restrict__ in, const float* __restrict__ w1,
                                float* __restrict__ part) {
    __shared__ float in_s[8][8][40];
    __shared__ float w_s[8][8][49];
    int bx = blockIdx.x;               // 2048 blocks
    int s   = bx >> 6;
    int r6  = bx & 63;
    int img = r6 >> 3;
    int oc0 = (r6 & 7) * 8;
    int tid = threadIdx.x;

    for (int idx = tid; idx < 2560; idx += 256) {
        int col = idx % 40;
        int row = (idx / 40) & 7;
        int ic  = idx / 320;
        float v = 0.f;
        if (row >= 3 && col >= 3 && col < 35)
            v = in[((size_t)(img * 256 + s * 8 + ic) * 32 + (row - 3)) * 32 + (col - 3)];
        in_s[ic][row][col] = v;
    }
    for (int idx = tid; idx < 3136; idx += 256) {
        int ocl = idx / 392;
        int rem = idx % 392;
        int ic  = rem / 49;
        int k   = rem % 49;
        w_s[ocl][ic][k] = w1[((size_t)(oc0 + ocl) * 256 + s * 8 + ic) * 49 + k];
    }
    __syncthreads();

    int c  = tid & 31;
    int r  = (tid >> 5) & 1;
    int ol = tid >> 6;
    float a0 = 0.f, a1 = 0.f;
    for (int ic = 0; ic < 8; ++ic) {
        const float* wA = &w_s[ol][ic][0];
        const float* wB = &w_s[ol + 4][ic][0];
#pragma unroll
        for (int kr = 0; kr < 7; ++kr) {
            const float* ip = &in_s[ic][r + kr][c];
#pragma unroll
            for (int kc = 0; kc < 7; ++kc) {
                float iv = ip[kc];
                a0 += iv * wA[kr * 7 + kc];
                a1 += iv * wB[kr * 7 + kc];
            }
        }
    }
    size_t base = (size_t)s * 32768 + img * 4096 + (oc0 + ol) * 64 + r * 32 + c;
    part[base]       = a0;
    part[base + 256] = a1;
}

__global__ void conv1_reduce_k(const float* __restrict__ part, float* __restrict__ conv1) {
    int o = blockIdx.x * blockDim.x + threadIdx.x;   // 32768
    float a = 0.f;
#pragma unroll
    for (int s = 0; s < 32; ++s) a += part[(size_t)s * 32768 + o];
    conv1[o] = fmaxf(a, 0.f);
}

// ---------------- conv2: row 0, split-K 8 x 8ic, LDS-staged upsampled rows -------
__global__ void conv2_partial_k(const float* __restrict__ conv1, const float* __restrict__ w2,
                                float* __restrict__ part) {
    __shared__ float up_s[8][4][72];
    __shared__ float w_s2[4][8][49];
    int bx = blockIdx.x;               // 1024 blocks
    int s   = bx >> 7;
    int r7  = bx & 127;
    int img = r7 >> 4;
    int oc0 = (r7 & 15) * 4;
    int tid = threadIdx.x;

    for (int idx = tid; idx < 2304; idx += 256) {
        int col = idx % 72;
        int ur  = (idx / 72) & 3;
        int ic  = idx / 288;
        float v = 0.f;
        if (col >= 3 && col < 67)
            v = conv1[(size_t)(img * 64 + s * 8 + ic) * 64 + (ur >> 1) * 32 + ((col - 3) >> 1)];
        up_s[ic][ur][col] = v;
    }
    for (int idx = tid; idx < 1568; idx += 256) {
        int ocl = idx / 392;
        int rem = idx % 392;
        int ic  = rem / 49;
        int k   = rem % 49;
        w_s2[ocl][ic][k] = w2[((size_t)(oc0 + ocl) * 64 + s * 8 + ic) * 49 + k];
    }
    __syncthreads();

    int c2 = tid & 63;
    int ol = tid >> 6;
    float acc = 0.f;
    for (int ic = 0; ic < 8; ++ic) {
#pragma unroll
        for (int ur = 0; ur < 4; ++ur) {
            const float* ip = &up_s[ic][ur][c2];
            const float* wr = &w_s2[ol][ic][(ur + 3) * 7];
#pragma unroll
            for (int kc = 0; kc < 7; ++kc) acc += ip[kc] * wr[kc];
        }
    }
    part[(size_t)s * 32768 + img * 4096 + (oc0 + ol) * 64 + c2] = acc;
}

__global__ void conv2_reduce_k(const float* __restrict__ part, float* __restrict__ conv2) {
    int o = blockIdx.x * blockDim.x + threadIdx.x;   // 32768
    float a = 0.f;
#pragma unroll
    for (int s = 0; s < 8; ++s) a += part[(size_t)s * 32768 + o];
    conv2[o] = fmaxf(a, 0.f);
}

// ---------------- conv3: row 0, split-K 4 x 16ic, LDS-staged ---------------------
__global__ void conv3_partial_k(const float* __restrict__ conv2, const float* __restrict__ w3,
                                float* __restrict__ part) {
    __shared__ float row_s[16][132];
    __shared__ float wc_s[2][16][4];
    int bx = blockIdx.x;               // 4096 blocks
    int s    = bx >> 10;
    int r10  = bx & 1023;
    int img  = r10 >> 7;
    int oc0  = (r10 & 127) * 2;
    int tid  = threadIdx.x;

    for (int idx = tid; idx < 2112; idx += 256) {
        int col = idx % 132;
        int ic  = idx / 132;
        float v = 0.f;
        if (col >= 1 && col < 129)
            v = conv2[(size_t)(img * 64 + s * 16 + ic) * 64 + ((col - 1) >> 1)];
        row_s[ic][col] = v;
    }
    if (tid < 96) {
        int ocl = tid / 48;
        int ic  = (tid / 3) % 16;
        int kc  = tid % 3;
        const float* wp = w3 + ((size_t)(oc0 + ocl) * 64 + s * 16 + ic) * 9;
        wc_s[ocl][ic][kc] = wp[3 + kc] + wp[6 + kc];
    }
    __syncthreads();

    int c3 = tid & 127;
    int ol = tid >> 7;
    float acc = 0.f;
    for (int ic = 0; ic < 16; ++ic) {
        const float* ip = &row_s[ic][c3];
#pragma unroll
        for (int kc = 0; kc < 3; ++kc) acc += ip[kc] * wc_s[ol][ic][kc];
    }
    part[(size_t)s * 262144 + img * 32768 + (oc0 + ol) * 128 + c3] = acc;
}

__global__ void conv3_reduce_k(const float* __restrict__ part, float* __restrict__ conv3) {
    int o = blockIdx.x * blockDim.x + threadIdx.x;   // 262,144
    float a = part[o] + part[262144 + o] + part[524288 + o] + part[786432 + o];
    conv3[o] = fmaxf(a, 0.f);
}

// ---------------- bilinear align_corners x-upsample of row 0: 128 -> 256 ---------
__global__ void bilin_k(const float* __restrict__ conv3, float* __restrict__ fm) {
    int o = blockIdx.x * blockDim.x + threadIdx.x;   // 524288 = (img*256+d)*256+x
    int x = o & 255;
    int rest = o >> 8;
    const float f = (float)(127.0 / 255.0);
    float pos = (float)x * f;
    float i0f = floorf(pos);
    int i0 = (int)i0f;
    int i1 = min(i0 + 1, 127);
    float w = pos - i0f;
    const float* rp = conv3 + (size_t)rest * 128;
    fm[o] = rp[i0] * (1.f - w) + rp[i1] * w;
}

// ---------------- pixel-math table: per (b,n,p) -> {ws0, ws1, x0c, x1c} ----------
// Identical float op sequence to previous rounds (faithful gy-from-gx bug).
__global__ void pixtab_k(const float* __restrict__ pix, float* __restrict__ ptab) {
    int t = blockIdx.x * 256 + threadIdx.x;          // 240,000
    if (t >= NB * NN * NP) return;
    float px = pix[(size_t)t * 2];
    float gx = px / 256.0f - 1.0f;
    float gy = gx / 256.0f - 1.0f;
    float ix = ((gx + 1.0f) * 256.0f - 1.0f) * 0.5f;
    float iy = ((gy + 1.0f) * 256.0f - 1.0f) * 0.5f;
    float x0f = floorf(ix), y0f = floorf(iy);
    int x0 = (int)x0f, y0 = (int)y0f;
    float wx1 = ix - x0f, wy1 = iy - y0f;
    float wrow = 0.f;                                // weight landing on fmap row 0
    if (y0 == 0) wrow += 1.0f - wy1;
    if (y0 + 1 == 0) wrow += wy1;
    wrow *= 0.25f;                                   // fold mean over N=4
    bool ok0 = (x0 >= 0) && (x0 < 256);
    int x1 = x0 + 1;
    bool ok1 = (x1 >= 0) && (x1 < 256);
    float4 v;
    v.x = ok0 ? wrow * (1.0f - wx1) : 0.f;
    v.y = ok1 ? wrow * wx1 : 0.f;
    v.z = __int_as_float(min(max(x0, 0), 255));
    v.w = __int_as_float(min(max(x1, 0), 255));
    ((float4*)ptab)[t] = v;
}

// ---------------- per-voxel point lists (only 60K atomics) -----------------------
__global__ void listbuild_k(const int* __restrict__ vox, unsigned* __restrict__ cntI,
                            unsigned* __restrict__ idx2) {
    int r = blockIdx.x * 256 + threadIdx.x;          // 60,000
    if (r >= NROWS) return;
    int v0 = vox[3 * r], v1 = vox[3 * r + 1], v2 = vox[3 * r + 2];
    int b = (r >= NP) ? 1 : 0;
    int lin = ((b * 60 + v0) * 60 + v1) * 8 + v2;
    unsigned slot = atomicAdd(&cntI[lin], 1u);
    if (slot < CAP) idx2[(size_t)lin * CAP + slot] = (unsigned)r;
}

// ---------------- sample + mean-over-n + BN stats; S stored bf16 -----------------
// S flat (b,d,p) IS feats (60000,256) row-major (the .view bug = free reshape).
__global__ void sample_k(const float* __restrict__ fm, const float* __restrict__ ptab,
                         unsigned short* __restrict__ Sbf, double* __restrict__ sum,
                         double* __restrict__ sumsq) {
    __shared__ __align__(16) unsigned short rows_bf[4][256][DG];  // 16 KB
    __shared__ float bsum[256], bsq[256];
    int bx = blockIdx.x;            // b*32 + dgroup
    int b  = bx >> 5;
    int d0 = (bx & 31) * DG;
    int tid = threadIdx.x;

#pragma unroll
    for (int i = 0; i < 32; ++i) {
        int dd = i & 7;
        int n  = i >> 3;
        rows_bf[n][tid][dd] = f2bf(fm[((size_t)((b * 4 + n) * 256 + d0 + dd)) * 256 + tid]);
    }
    bsum[tid] = 0.f;
    bsq[tid]  = 0.f;
    __syncthreads();

    const int CHUNK = 1000;         // 30 y-chunks
    int p0 = blockIdx.y * CHUNK;
    float lsum[DG], lsq[DG];
#pragma unroll
    for (int dd = 0; dd < DG; ++dd) { lsum[dd] = 0.f; lsq[dd] = 0.f; }

    const float4* pt = (const float4*)ptab + (size_t)(b * 4) * NP;
    unsigned short* Sb = Sbf + (size_t)b * (ND * NP);

    for (int p = p0 + tid; p < p0 + CHUNK; p += 256) {
        float acc[DG];
#pragma unroll
        for (int dd = 0; dd < DG; ++dd) acc[dd] = 0.f;
#pragma unroll
        for (int n = 0; n < 4; ++n) {
            float4 tv = pt[(size_t)n * NP + p];
            float ws0 = tv.x, ws1 = tv.y;
            int x0c = __float_as_int(tv.z);
            int x1c = __float_as_int(tv.w);
            uint4 q0 = *(const uint4*)&rows_bf[n][x0c][0];
            uint4 q1 = *(const uint4*)&rows_bf[n][x1c][0];
#define ACC2(j, w0r, w1r)                                                        \
            acc[2*(j)]   += ws0 * __uint_as_float((w0r) << 16)                    \
                          + ws1 * __uint_as_float((w1r) << 16);                   \
            acc[2*(j)+1] += ws0 * __uint_as_float((w0r) & 0xFFFF0000u)            \
                          + ws1 * __uint_as_float((w1r) & 0xFFFF0000u);
            ACC2(0, q0.x, q1.x)
            ACC2(1, q0.y, q1.y)
            ACC2(2, q0.z, q1.z)
            ACC2(3, q0.w, q1.w)
#undef ACC2
        }
#pragma unroll
        for (int dd = 0; dd < DG; ++dd) {
            float a = acc[dd];
            Sb[(size_t)(d0 + dd) * NP + p] = f2bf(a);
            lsum[dd] += a;
            lsq[dd]  += a * a;
        }
    }
    // block-level BN-stat reduction: cc(tid) bijective per dd -> no LDS contention
#pragma unroll
    for (int dd = 0; dd < DG; ++dd) {
        int cc = (48 * (d0 + dd) + p0 + tid) & 255;
        atomicAdd(&bsum[cc], lsum[dd]);
        atomicAdd(&bsq[cc], lsq[dd]);
    }
    __syncthreads();
    atomicAdd(&sum[tid], (double)bsum[tid]);
    atomicAdd(&sumsq[tid], (double)bsq[tid]);
}

__global__ void scaleshift_k(const double* __restrict__ sum, const double* __restrict__ sumsq,
                             const float* __restrict__ gamma, const float* __restrict__ beta,
                             float* __restrict__ scale, float* __restrict__ shift) {
    int d = threadIdx.x;
    double mu = sum[d] / 60000.0;
    double var = sumsq[d] / 60000.0 - mu * mu;
    float rs = 1.0f / sqrtf((float)var + 1e-5f);
    float sc = rs * gamma[d];
    scale[d] = sc;
    shift[d] = beta[d] - (float)mu * sc;
}

// ---------------- gather: block per voxel, plain stores (no atomics, no memset) --
__global__ void gather_k(const unsigned short* __restrict__ Sbf,
                         const unsigned* __restrict__ cntI, const unsigned* __restrict__ idx2,
                         const float* __restrict__ scale, const float* __restrict__ shift,
                         float* __restrict__ out, float* __restrict__ coors) {
    int v = blockIdx.x;             // 0..57599
    int tid = threadIdx.x;
    unsigned k = cntI[v];
    unsigned kk = (k < CAP) ? k : CAP;
    float acc = 0.f;
    for (unsigned i = 0; i < kk; ++i) {
        unsigned r = idx2[(size_t)v * CAP + i];
        acc += bf2f(Sbf[(size_t)r * 256 + tid]);    // feats row r is contiguous
    }
    float val = 0.f;
    if (k) val = fmaf(acc / (float)k, scale[tid], shift[tid]);
    out[(size_t)v * 256 + tid] = val;               // empty voxels: exact 0
    if (tid < 4) {
        int bb = v / 28800, rr = v % 28800;
        int x = (tid == 0) ? bb : (tid == 1) ? rr / 480 : (tid == 2) ? (rr % 480) / 8 : rr % 8;
        coors[(size_t)v * 4 + tid] = (float)x;
    }
}

extern "C" void kernel_launch(void* const* d_in, const int* in_sizes, int n_in,
                              void* d_out, int out_size, void* d_ws, size_t ws_size,
                              hipStream_t stream) {
    const float* clip  = (const float*)d_in[0];
    const float* pix   = (const float*)d_in[1];
    const int*   vox   = (const int*)d_in[2];
    const float* w1    = (const float*)d_in[3];
    const float* w2    = (const float*)d_in[4];
    const float* w3    = (const float*)d_in[5];
    const float* gamma = (const float*)d_in[6];
    const float* beta  = (const float*)d_in[7];
    float* out = (float*)d_out;
    float* ws  = (float*)d_ws;

    unsigned short* Sbf = (unsigned short*)(ws + OFF_SBF);
    float*    c1p   = ws + OFF_C1P;
    float*    c2p   = ws + OFF_C2P;
    float*    c3p   = ws + OFF_C3P;
    float*    c1    = ws + OFF_C1;
    float*    c2    = ws + OFF_C2;
    float*    c3    = ws + OFF_C3;
    float*    fm    = ws + OFF_FM;
    float*    ptab  = ws + OFF_PTAB;
    unsigned* cntI  = (unsigned*)(ws + OFF_CNTI);
    unsigned* idx2  = (unsigned*)(ws + OFF_IDX2);
    float*    scale = ws + OFF_SCALE;
    float*    shift = ws + OFF_SHIFT;
    double*   sum   = (double*)(ws + OFF_SUM);
    double*   sumsq = (double*)(ws + OFF_SUMSQ);

    // zero only the small accumulators (no 59 MB out memset anymore)
    hipMemsetAsync((void*)cntI, 0, NSEG * sizeof(unsigned), stream);
    hipMemsetAsync((void*)sum, 0, 2 * 256 * sizeof(double), stream);

    conv1_partial_k<<<2048, 256, 0, stream>>>(clip, w1, c1p);
    conv1_reduce_k<<<128, 256, 0, stream>>>(c1p, c1);
    conv2_partial_k<<<1024, 256, 0, stream>>>(c1, w2, c2p);
    conv2_reduce_k<<<128, 256, 0, stream>>>(c2p, c2);
    conv3_partial_k<<<4096, 256, 0, stream>>>(c2, w3, c3p);
    conv3_reduce_k<<<1024, 256, 0, stream>>>(c3p, c3);
    bilin_k<<<2048, 256, 0, stream>>>(c3, fm);
    pixtab_k<<<(NB * NN * NP + 255) / 256, 256, 0, stream>>>(pix, ptab);
    listbuild_k<<<(NROWS + 255) / 256, 256, 0, stream>>>(vox, cntI, idx2);
    sample_k<<<dim3(64, 30), 256, 0, stream>>>(fm, ptab, Sbf, sum, sumsq);
    scaleshift_k<<<1, 256, 0, stream>>>(sum, sumsq, gamma, beta, scale, shift);
    gather_k<<<NSEG, 256, 0, stream>>>(Sbf, cntI, idx2, scale, shift,
                                       out, out + (size_t)NSEG * 256);
}